// Round 1
// baseline (75661.615 us; speedup 1.0000x reference)
//
#include <hip/hip_runtime.h>
#include <stdint.h>

#define TSEQ 32768
#define HDIM 512
#define NWGL 64         // workgroups per layer
#define DPW  8          // hidden dims per workgroup
#define POISON32 0x7FA55A5Au   // NaN payload; real values are provably finite

__device__ __forceinline__ float sigf(float x){ return 1.f/(1.f+__expf(-x)); }
__device__ __forceinline__ float tanhf_fast(float x){ return 1.f - 2.f/(1.f+__expf(2.f*x)); }

__device__ __forceinline__ uint32_t agload(uint32_t* p){
  return __hip_atomic_load(p, __ATOMIC_RELAXED, __HIP_MEMORY_SCOPE_AGENT);
}
__device__ __forceinline__ void agstore(uint32_t* p, uint32_t v){
  __hip_atomic_store(p, v, __ATOMIC_RELAXED, __HIP_MEMORY_SCOPE_AGENT);
}

// ---- poison hs0/hs1 with agent-scope stores (no dirty L2 copies left behind) ----
__global__ __launch_bounds__(256,1)
void poison_kernel(uint64_t* __restrict__ a, uint64_t* __restrict__ b, int n64){
  const uint64_t P = (((uint64_t)POISON32)<<32) | (uint64_t)POISON32;
  int i = blockIdx.x*256 + threadIdx.x;
  const int st = gridDim.x*256;
  for (; i < n64; i += st){
    __hip_atomic_store(a+i, P, __ATOMIC_RELAXED, __HIP_MEMORY_SCOPE_AGENT);
    __hip_atomic_store(b+i, P, __ATOMIC_RELAXED, __HIP_MEMORY_SCOPE_AGENT);
  }
}

// ---- persistent 2-layer LSTM scan, data-flow synchronized ----
// grid = 128 wgs: wg<64 -> layer0 (input x), wg>=64 -> layer1 (input hs0)
// thread: r = tid&31 (gate row within wg: gate=r>>3, dim=r&7), c = tid>>5 (64-wide K-chunk)
__global__ __launch_bounds__(256,1)
void lstm_persistent(const float* __restrict__ x,
                     const float* __restrict__ wih0, const float* __restrict__ whh0,
                     const float* __restrict__ bih0, const float* __restrict__ bhh0,
                     const float* __restrict__ wih1, const float* __restrict__ whh1,
                     const float* __restrict__ bih1, const float* __restrict__ bhh1,
                     float* __restrict__ hs0, float* __restrict__ hs1)
{
  const int wg    = blockIdx.x;
  const int layer = (wg >= NWGL) ? 1 : 0;
  const int wgl   = layer ? wg - NWGL : wg;
  const int tid   = threadIdx.x;
  const int r     = tid & 31;
  const int c     = tid >> 5;

  const float* Wih = layer ? wih1 : wih0;
  const float* Whh = layer ? whh1 : whh0;
  float* dst = layer ? hs1 : hs0;      // own layer output == own recurrent source

  const int grow = (r>>3)*HDIM + wgl*DPW + (r&7);   // global gate-row in [0,2048)

  // register-resident weight slices: 64 f32 each of W_ih and W_hh for (row=grow, k in [c*64, c*64+64))
  float4 wi[16], wr[16];
  #pragma unroll
  for (int q=0;q<16;q++){
    wi[q] = *(const float4*)&Wih[(size_t)grow*HDIM + c*64 + q*4];
    wr[q] = *(const float4*)&Whh[(size_t)grow*HDIM + c*64 + q*4];
  }
  float bias = 0.f;
  if (tid < 32) bias = (layer?bih1:bih0)[grow] + (layer?bhh1:bhh0)[grow];

  float cstate = 0.f;   // valid for tid<8 (one hidden dim each)

  __shared__ float ha[HDIM];    // step input vector (x[t] or hs0[t])
  __shared__ float hr[HDIM];    // recurrent vector h[t-1]
  __shared__ float part[128];
  __shared__ float gl[32];

  float4 xpref = make_float4(0.f,0.f,0.f,0.f);
  if (!layer && tid >= 128) xpref = *(const float4*)&x[(tid-128)*4];

  #pragma unroll 1
  for (int t = 0; t < TSEQ; ++t){
    // stage layer-0 input (prefetched last iteration)
    if (!layer && tid >= 128) *(float4*)&ha[(tid-128)*4] = xpref;

    // ---- availability spin (data-as-flag, per-thread independent) ----
    if (t > 0 && tid < 128){
      uint32_t* p = (uint32_t*)(dst + (size_t)(t-1)*HDIM) + tid*4;
      uint32_t v0,v1,v2,v3;
      do {
        v0 = agload(p+0); v1 = agload(p+1); v2 = agload(p+2); v3 = agload(p+3);
      } while ((v0==POISON32)|(v1==POISON32)|(v2==POISON32)|(v3==POISON32));
      float4 f; f.x=__uint_as_float(v0); f.y=__uint_as_float(v1);
                f.z=__uint_as_float(v2); f.w=__uint_as_float(v3);
      *(float4*)&hr[tid*4] = f;
    }
    if (layer && tid >= 128){
      uint32_t* p = (uint32_t*)(hs0 + (size_t)t*HDIM) + (tid-128)*4;
      uint32_t v0,v1,v2,v3;
      do {
        v0 = agload(p+0); v1 = agload(p+1); v2 = agload(p+2); v3 = agload(p+3);
      } while ((v0==POISON32)|(v1==POISON32)|(v2==POISON32)|(v3==POISON32));
      float4 f; f.x=__uint_as_float(v0); f.y=__uint_as_float(v1);
                f.z=__uint_as_float(v2); f.w=__uint_as_float(v3);
      *(float4*)&ha[(tid-128)*4] = f;
    }
    if (t == 0 && tid < 128) *(float4*)&hr[tid*4] = make_float4(0.f,0.f,0.f,0.f);
    __syncthreads();

    // prefetch next x row (off critical path)
    if (!layer && tid >= 128 && (t+1) < TSEQ)
      xpref = *(const float4*)&x[(size_t)(t+1)*HDIM + (tid-128)*4];

    // ---- matvec: g[row] partial over this thread's 64-wide K chunk ----
    float s0=0.f,s1=0.f,s2=0.f,s3=0.f;
    const float4* hr4 = (const float4*)(hr + c*64);
    const float4* ha4 = (const float4*)(ha + c*64);
    #pragma unroll
    for (int q=0;q<16;q++){
      float4 hv = hr4[q];
      s0 = fmaf(wr[q].x, hv.x, s0); s1 = fmaf(wr[q].y, hv.y, s1);
      s2 = fmaf(wr[q].z, hv.z, s2); s3 = fmaf(wr[q].w, hv.w, s3);
      float4 av = ha4[q];
      s0 = fmaf(wi[q].x, av.x, s0); s1 = fmaf(wi[q].y, av.y, s1);
      s2 = fmaf(wi[q].z, av.z, s2); s3 = fmaf(wi[q].w, av.w, s3);
    }
    float acc = (s0+s1)+(s2+s3);
    acc += __shfl_xor(acc, 32);
    if ((tid & 63) < 32) part[(tid>>6)*32 + (tid&31)] = acc;
    __syncthreads();
    if (tid < 32) gl[tid] = part[tid] + part[32+tid] + part[64+tid] + part[96+tid] + bias;
    __syncthreads();
    if (tid < 8){
      float gi = sigf(gl[tid]);
      float gf = sigf(gl[8+tid]);
      float gg = tanhf_fast(gl[16+tid]);
      float go = sigf(gl[24+tid]);
      cstate = fmaf(gf, cstate, gi*gg);
      float h = go * tanhf_fast(cstate);
      agstore((uint32_t*)(dst + (size_t)t*HDIM + wgl*DPW + tid), __float_as_uint(h));
    }
    // no trailing barrier needed: next iteration's LDS writes are ordered behind
    // barriers that all threads (incl. tid<8 readers of gl) must pass first
  }
}

// ---- head ----
__global__ __launch_bounds__(256)
void transpose_kernel(const float* __restrict__ w1, const float* __restrict__ w2,
                      float* __restrict__ w1t, float* __restrict__ w2t){
  int i = blockIdx.x*256 + threadIdx.x;
  if (i < 128*512){ int rr = i >> 9, k = i & 511; w1t[k*128 + rr] = w1[i]; }
  if (i < 64*128){ int rr = i >> 7, k = i & 127; w2t[k*64 + rr] = w2[i]; }
}

__global__ __launch_bounds__(128)
void mlp1_kernel(const float* __restrict__ hs1, const float* __restrict__ w1t,
                 const float* __restrict__ b1, float* __restrict__ z1){
  __shared__ float hsl[2048];             // 4 rows x 512
  const int tid = threadIdx.x;
  const size_t row0 = (size_t)blockIdx.x*4;
  #pragma unroll
  for (int q=0;q<4;q++){
    int idx = tid + q*128;
    *(float4*)&hsl[idx*4] = *(const float4*)&hs1[row0*512 + idx*4];
  }
  __syncthreads();
  float a0=0.f,a1=0.f,a2=0.f,a3=0.f;
  #pragma unroll 4
  for (int k=0;k<512;k++){
    float wv = w1t[k*128 + tid];
    a0 = fmaf(wv, hsl[k],      a0);
    a1 = fmaf(wv, hsl[512+k],  a1);
    a2 = fmaf(wv, hsl[1024+k], a2);
    a3 = fmaf(wv, hsl[1536+k], a3);
  }
  float bb = b1[tid];
  z1[(row0+0)*128 + tid] = fmaxf(a0+bb, 0.f);
  z1[(row0+1)*128 + tid] = fmaxf(a1+bb, 0.f);
  z1[(row0+2)*128 + tid] = fmaxf(a2+bb, 0.f);
  z1[(row0+3)*128 + tid] = fmaxf(a3+bb, 0.f);
}

template<int NF_>
__global__ void stats_partial(const float* __restrict__ z, float* __restrict__ part){
  const int cf = threadIdx.x;
  const int b  = blockIdx.x;             // 64 blocks x 512 rows
  float s=0.f, sq=0.f;
  const float* p = z + (size_t)b*512*NF_ + cf;
  for (int rr=0; rr<512; rr++){
    float v = p[(size_t)rr*NF_];
    s += v; sq = fmaf(v, v, sq);
  }
  part[(b*NF_ + cf)*2+0] = s;
  part[(b*NF_ + cf)*2+1] = sq;
}

template<int NF_>
__global__ void stats_final(const float* __restrict__ part, const float* __restrict__ gamma,
                            const float* __restrict__ beta, float* __restrict__ sc,
                            float* __restrict__ sh){
  const int cf = threadIdx.x;
  float s=0.f, sq=0.f;
  for (int b=0;b<64;b++){ s += part[(b*NF_+cf)*2]; sq += part[(b*NF_+cf)*2+1]; }
  const float inv = 1.f/32768.f;
  float m = s*inv;
  float v = fmaf(sq, inv, -m*m);
  float scale = gamma[cf]*rsqrtf(v + 1e-5f);
  sc[cf] = scale;
  sh[cf] = fmaf(-m, scale, beta[cf]);
}

__global__ __launch_bounds__(64)
void mlp2_kernel(const float* __restrict__ z1, const float* __restrict__ w2t,
                 const float* __restrict__ b2, const float* __restrict__ sc1,
                 const float* __restrict__ sh1, float* __restrict__ z2){
  __shared__ float zl[1024];              // 8 rows x 128 (BN-applied)
  const int tid = threadIdx.x;
  const size_t row0 = (size_t)blockIdx.x*8;
  #pragma unroll
  for (int q=0;q<4;q++){
    int idx = tid + q*64;                 // float4 index 0..255
    float4 v = *(const float4*)&z1[row0*128 + idx*4];
    int k0 = (idx*4) & 127;
    v.x = fmaf(v.x, sc1[k0+0], sh1[k0+0]);
    v.y = fmaf(v.y, sc1[k0+1], sh1[k0+1]);
    v.z = fmaf(v.z, sc1[k0+2], sh1[k0+2]);
    v.w = fmaf(v.w, sc1[k0+3], sh1[k0+3]);
    *(float4*)&zl[idx*4] = v;
  }
  __syncthreads();
  float acc[8] = {0.f,0.f,0.f,0.f,0.f,0.f,0.f,0.f};
  #pragma unroll 4
  for (int k=0;k<128;k++){
    float wv = w2t[k*64 + tid];
    #pragma unroll
    for (int rr=0;rr<8;rr++) acc[rr] = fmaf(wv, zl[rr*128 + k], acc[rr]);
  }
  float bb = b2[tid];
  #pragma unroll
  for (int rr=0;rr<8;rr++)
    z2[(row0+rr)*64 + tid] = fmaxf(acc[rr]+bb, 0.f);
}

__global__ __launch_bounds__(256)
void mlp3_kernel(const float* __restrict__ z2, const float* __restrict__ w3,
                 const float* __restrict__ b3, const float* __restrict__ sc2,
                 const float* __restrict__ sh2, float* __restrict__ out){
  const int tid = threadIdx.x;
  const int lane = tid & 63;
  const size_t row = (size_t)blockIdx.x*4 + (tid>>6);   // one wave per row
  float v = fmaf(z2[row*64 + lane], sc2[lane], sh2[lane]);
  float p0 = v*w3[lane], p1 = v*w3[64+lane], p2 = v*w3[128+lane];
  #pragma unroll
  for (int off=32; off; off>>=1){
    p0 += __shfl_xor(p0, off);
    p1 += __shfl_xor(p1, off);
    p2 += __shfl_xor(p2, off);
  }
  if (lane == 0){
    out[row*3+0] = p0 + b3[0];
    out[row*3+1] = p1 + b3[1];
    out[row*3+2] = p2 + b3[2];
  }
}

extern "C" void kernel_launch(void* const* d_in, const int* in_sizes, int n_in,
                              void* d_out, int out_size, void* d_ws, size_t ws_size,
                              hipStream_t stream){
  (void)in_sizes; (void)n_in; (void)out_size;
  const float* x    = (const float*)d_in[0];
  const float* wih0 = (const float*)d_in[1];
  const float* whh0 = (const float*)d_in[2];
  const float* bih0 = (const float*)d_in[3];
  const float* bhh0 = (const float*)d_in[4];
  const float* wih1 = (const float*)d_in[5];
  const float* whh1 = (const float*)d_in[6];
  const float* bih1 = (const float*)d_in[7];
  const float* bhh1 = (const float*)d_in[8];
  const float* w1   = (const float*)d_in[9];
  const float* b1   = (const float*)d_in[10];
  const float* g1   = (const float*)d_in[11];
  const float* be1  = (const float*)d_in[12];
  const float* w2   = (const float*)d_in[13];
  const float* b2   = (const float*)d_in[14];
  const float* g2   = (const float*)d_in[15];
  const float* be2  = (const float*)d_in[16];
  const float* w3   = (const float*)d_in[17];
  const float* b3   = (const float*)d_in[18];
  float* ws  = (float*)d_ws;
  float* out = (float*)d_out;

  if (ws_size < (size_t)33554432ull*4ull) return;   // need 134.2 MB

  float* hs0  = ws;                   // [32768][512]
  float* hs1  = ws + 16777216;        // [32768][512]
  // scratch below aliases hs0 (dead after the persistent kernel):
  float* z1    = ws;                  // [32768][128]
  float* z2    = ws + 4194304;        // [32768][64]
  float* w1t   = ws + 6291456;        // [512][128]
  float* w2t   = ws + 6356992;        // [128][64]
  float* part1 = ws + 6365184;        // [64][128][2]
  float* part2 = ws + 6381568;        // [64][64][2]
  float* sc1   = ws + 6389760;
  float* sh1   = sc1 + 128;
  float* sc2   = sh1 + 128;
  float* sh2   = sc2 + 64;

  poison_kernel<<<1024, 256, 0, stream>>>((uint64_t*)hs0, (uint64_t*)hs1, 8388608);
  lstm_persistent<<<128, 256, 0, stream>>>(x, wih0, whh0, bih0, bhh0,
                                           wih1, whh1, bih1, bhh1, hs0, hs1);
  transpose_kernel<<<256, 256, 0, stream>>>(w1, w2, w1t, w2t);
  mlp1_kernel<<<8192, 128, 0, stream>>>(hs1, w1t, b1, z1);
  stats_partial<128><<<64, 128, 0, stream>>>(z1, part1);
  stats_final<128><<<1, 128, 0, stream>>>(part1, g1, be1, sc1, sh1);
  mlp2_kernel<<<4096, 64, 0, stream>>>(z1, w2t, b2, sc1, sh1, z2);
  stats_partial<64><<<64, 64, 0, stream>>>(z2, part2);
  stats_final<64><<<1, 64, 0, stream>>>(part2, g2, be2, sc2, sh2);
  mlp3_kernel<<<8192, 256, 0, stream>>>(z2, w3, b3, sc2, sh2, out);
}